// Round 1
// 99.434 us; speedup vs baseline: 1.3153x; 1.3153x over previous
//
#include <hip/hip_runtime.h>
#include <math.h>

// Chamfer distance via MFMA on MI355X (gfx950).
// B=8, N=M=8192, fp32 in/out. out = concat(dist1[B*N], dist2[B*M]).
//
// d(q,c) = |q|^2 + (|c|^2 - 2 q.c). The parenthesized part is computed as a
// K<=16 dot product on v_mfma_f32_32x32x16_bf16 using split-bf16 (hi+lo)
// operands; all four cross terms (qh*eh, qh*el, ql*eh, ql*el) are kept, plus
// |c|^2 embedded hi/lo against 1.0 — error ~2^-18 relative per term.
// bf16 x bf16 products are exact in the f32 accumulator.
//
// Kernel 1 pre-transforms candidates into MFMA A-fragment order in d_ws
// (needs B*(pad512(N)+pad512(M))*32 = 4 MB at 8192) so kernel 2's staging is a
// linear global_load_lds copy. Each wave holds TWO query B-fragments (64
// queries) so each A-fragment ds_read_b128 feeds 2 MFMAs (keeps the LDS pipe
// under the MFMA pipe: 12cyc/read vs 2x32cyc/MFMA per SIMD).
// Each block scans ALL candidates for its 256 queries -> plain stores, no
// atomics, no memset.

typedef __attribute__((ext_vector_type(8))) short short8;
typedef __attribute__((ext_vector_type(16))) float f32x16;

#define CTC    512               // candidates per LDS tile
#define TILEB  (CTC * 32)        // 16 KB (CTC/32 groups x 1024 B)
#define NGRP   (CTC / 32)        // 16 groups per tile

__host__ __device__ static inline size_t pad512(size_t x) {
  return (x + 511) & ~(size_t)511;
}

__device__ __forceinline__ unsigned short bf16h(float x) {
  unsigned u = __float_as_uint(x);
  return (unsigned short)((u + 0x7fffu + ((u >> 16) & 1u)) >> 16);  // RNE
}
__device__ __forceinline__ float bf16f(unsigned short h) {
  return __uint_as_float((unsigned)h << 16);
}
__device__ __forceinline__ float m3(float a, float b, float c) {
  return fminf(fminf(a, b), c);  // -> v_min3_f32
}
__device__ __forceinline__ float red16(const f32x16& d, float mm) {
  float r0 = m3(d[0], d[1], d[2]);
  float r1 = m3(d[3], d[4], d[5]);
  float r2 = m3(d[6], d[7], d[8]);
  float r3 = m3(d[9], d[10], d[11]);
  float r4 = m3(d[12], d[13], d[14]);
  return m3(m3(r0, r1, r2), m3(r3, r4, d[15]), mm);   // 8 x v_min3 total
}

#define GLOAD_LDS16(gp, sp)                                                   \
  __builtin_amdgcn_global_load_lds(                                           \
      (const __attribute__((address_space(1))) unsigned int*)(gp),            \
      (__attribute__((address_space(3))) unsigned int*)(sp), 16, 0, 0)

// ---------------------------------------------------------------------------
// Kernel 1: transform candidate points into A-fragment layout.
// Per candidate j (group g=j>>5, row r=j&31), two 16B fragments:
//   khalf0: [Eh.x,Eh.y,Eh.z, El.x,El.y,El.z, Eh.x,Eh.y]
//   khalf1: [Eh.z, El.x,El.y,El.z, sqh, sql, 0, 0]       (E = -2c, sq = |c|^2)
// stored at frag16[g*64 + h*32 + r] == consumer byte addr g*1024 + lane*16
// with lane = h*32 + r.
// ---------------------------------------------------------------------------
__global__ __launch_bounds__(256) void frag_kernel(
    const float* __restrict__ xyz1, const float* __restrict__ xyz2,
    char* __restrict__ frags, int B, int N, int M)
{
  const int z = blockIdx.z, dir = z / B, b = z % B;
  const size_t Mpad = pad512((size_t)M), Npad = pad512((size_t)N);
  const float* cp; char* reg_; int Nc; size_t Pc;
  if (dir == 0) {  // candidates = xyz2
    cp = xyz2 + (size_t)b * M * 3;
    reg_ = frags + (size_t)b * Mpad * 32;
    Nc = M; Pc = Mpad;
  } else {         // candidates = xyz1
    cp = xyz1 + (size_t)b * N * 3;
    reg_ = frags + (size_t)B * Mpad * 32 + (size_t)b * Npad * 32;
    Nc = N; Pc = Npad;
  }
  const size_t j = (size_t)blockIdx.x * 256 + threadIdx.x;
  if (j >= Pc) return;

  float x = 0.f, y = 0.f, zz = 0.f, sq = 3.0e38f;   // pad -> "infinitely far"
  if (j < (size_t)Nc) {
    x = cp[3 * j + 0]; y = cp[3 * j + 1]; zz = cp[3 * j + 2];
    sq = x * x; sq = fmaf(y, y, sq); sq = fmaf(zz, zz, sq);
  }
  const float ex = -2.f * x, ey = -2.f * y, ez = -2.f * zz;
  const unsigned short ehx = bf16h(ex); const unsigned short elx = bf16h(ex - bf16f(ehx));
  const unsigned short ehy = bf16h(ey); const unsigned short ely = bf16h(ey - bf16f(ehy));
  const unsigned short ehz = bf16h(ez); const unsigned short elz = bf16h(ez - bf16f(ehz));
  const unsigned short sh  = bf16h(sq); const unsigned short sl  = bf16h(sq - bf16f(sh));

  short8 f0, f1;
  f0[0] = (short)ehx; f0[1] = (short)ehy; f0[2] = (short)ehz; f0[3] = (short)elx;
  f0[4] = (short)ely; f0[5] = (short)elz; f0[6] = (short)ehx; f0[7] = (short)ehy;
  f1[0] = (short)ehz; f1[1] = (short)elx; f1[2] = (short)ely; f1[3] = (short)elz;
  f1[4] = (short)sh;  f1[5] = (short)sl;  f1[6] = 0;          f1[7] = 0;

  short8* fp = (short8*)reg_ + ((j >> 5) * 64 + (j & 31));
  fp[0]  = f0;    // khalf 0
  fp[32] = f1;    // khalf 1
}

// Query B-fragment (pairs slot-for-slot with the candidate fragment):
//   khalf0: [Qh.x,Qh.y,Qh.z, Qh.x,Qh.y,Qh.z, Ql.x,Ql.y]
//   khalf1: [Ql.z, Ql.x,Ql.y,Ql.z, 1.0, 1.0, 0, 0]
// Slot products sum to  q.(-2c) + |c|^2  exactly as packed.
__device__ __forceinline__ short8 make_qfrag(float x, float y, float z, int hi) {
  const unsigned short hx = bf16h(x); const unsigned short lx = bf16h(x - bf16f(hx));
  const unsigned short hy = bf16h(y); const unsigned short ly = bf16h(y - bf16f(hy));
  const unsigned short hz = bf16h(z); const unsigned short lz = bf16h(z - bf16f(hz));
  const unsigned short ONE = 0x3F80;
  short8 f;
  if (hi == 0) {
    f[0] = (short)hx; f[1] = (short)hy; f[2] = (short)hz; f[3] = (short)hx;
    f[4] = (short)hy; f[5] = (short)hz; f[6] = (short)lx; f[7] = (short)ly;
  } else {
    f[0] = (short)lz; f[1] = (short)lx; f[2] = (short)ly; f[3] = (short)lz;
    f[4] = (short)ONE; f[5] = (short)ONE; f[6] = 0; f[7] = 0;
  }
  return f;
}

// ---------------------------------------------------------------------------
// Kernel 2: 256 threads (4 waves). Each wave owns 64 queries (2 B-frags).
// Block scans all candidates in double-buffered 16KB LDS tiles.
// Per group: 1 ds_read_b128 -> 2 MFMA -> 2x8 v_min3.
// ---------------------------------------------------------------------------
__global__ __launch_bounds__(256, 2) void chamfer_mfma(
    const float* __restrict__ xyz1, const float* __restrict__ xyz2,
    const char* __restrict__ frags, float* __restrict__ out,
    int B, int N, int M)
{
  const int z = blockIdx.z, dir = z / B, b = z % B;
  const size_t Mpad = pad512((size_t)M), Npad = pad512((size_t)N);
  const float* qp; float* o; const char* fr; int Nq, Nc;
  if (dir == 0) {   // queries = xyz1, candidates = xyz2
    qp = xyz1 + (size_t)b * N * 3;
    o  = out + (size_t)b * N;
    fr = frags + (size_t)b * Mpad * 32;
    Nq = N; Nc = (int)Mpad;
  } else {          // queries = xyz2, candidates = xyz1
    qp = xyz2 + (size_t)b * M * 3;
    o  = out + (size_t)B * N + (size_t)b * M;
    fr = frags + (size_t)B * Mpad * 32 + (size_t)b * Npad * 32;
    Nq = M; Nc = (int)Npad;
  }
  if ((int)(blockIdx.x * 256) >= Nq) return;   // block-uniform early out

  const int lane = threadIdx.x & 63;
  const int wid  = threadIdx.x >> 6;
  const int hi   = lane >> 5;

  // ---- two query sets per wave ----
  const int qbase = blockIdx.x * 256 + wid * 64;
  const int n0 = qbase + (lane & 31);
  const int n1 = n0 + 32;
  const int n0c = n0 < Nq ? n0 : Nq - 1;
  const int n1c = n1 < Nq ? n1 : Nq - 1;
  const float q0x = qp[3 * n0c], q0y = qp[3 * n0c + 1], q0z = qp[3 * n0c + 2];
  const float q1x = qp[3 * n1c], q1y = qp[3 * n1c + 1], q1z = qp[3 * n1c + 2];
  float sqq0 = q0x * q0x; sqq0 = fmaf(q0y, q0y, sqq0); sqq0 = fmaf(q0z, q0z, sqq0);
  float sqq1 = q1x * q1x; sqq1 = fmaf(q1y, q1y, sqq1); sqq1 = fmaf(q1z, q1z, sqq1);
  const short8 bq0 = make_qfrag(q0x, q0y, q0z, hi);
  const short8 bq1 = make_qfrag(q1x, q1y, q1z, hi);

  __shared__ __align__(16) char lds[2][TILEB];
  const int ntiles = Nc / CTC;

  // stage tile 0 into buffer 0 (each wave covers 4 x 1KB slices)
  {
    const char* src = fr + wid * 1024 + lane * 16;
    char* dst = lds[0] + wid * 1024;
#pragma unroll
    for (int i = 0; i < 4; ++i)
      GLOAD_LDS16(src + i * 4096, dst + i * 4096);
  }

  f32x16 zacc = {0.f,0.f,0.f,0.f,0.f,0.f,0.f,0.f,0.f,0.f,0.f,0.f,0.f,0.f,0.f,0.f};
  float mm0 = 3.0e38f, mm1 = 3.0e38f;

  for (int t = 0; t < ntiles; ++t) {
    asm volatile("s_waitcnt vmcnt(0)" ::: "memory");
    __syncthreads();   // tile t staged & visible; buf t^1 free for next stage
    if (t + 1 < ntiles) {
      const char* src = fr + (size_t)(t + 1) * TILEB + wid * 1024 + lane * 16;
      char* dst = lds[(t + 1) & 1] + wid * 1024;
#pragma unroll
      for (int i = 0; i < 4; ++i)
        GLOAD_LDS16(src + i * 4096, dst + i * 4096);
    }
    const char* bc = lds[t & 1] + lane * 16;   // per-lane-contiguous: no bank conflicts
#pragma unroll 4
    for (int g = 0; g < NGRP; ++g) {
      const short8 fa = *(const short8*)(bc + g * 1024);
      const f32x16 da = __builtin_amdgcn_mfma_f32_32x32x16_bf16(fa, bq0, zacc, 0, 0, 0);
      const f32x16 db = __builtin_amdgcn_mfma_f32_32x32x16_bf16(fa, bq1, zacc, 0, 0, 0);
      mm0 = red16(da, mm0);
      mm1 = red16(db, mm1);
    }
  }

  // C layout (m74/m101): col = lane&31 (query), rows split across lane^32.
  mm0 = fminf(mm0, __shfl_xor(mm0, 32));
  mm1 = fminf(mm1, __shfl_xor(mm1, 32));
  if (lane < 32) {
    if (n0 < Nq) o[n0] = fmaxf(mm0 + sqq0, 0.f);
    if (n1 < Nq) o[n1] = fmaxf(mm1 + sqq1, 0.f);
  }
}

extern "C" void kernel_launch(void* const* d_in, const int* in_sizes, int n_in,
                              void* d_out, int out_size, void* d_ws, size_t ws_size,
                              hipStream_t stream) {
  const float* xyz1 = (const float*)d_in[0];
  const float* xyz2 = (const float*)d_in[1];
  float* out = (float*)d_out;

  const int B = 8;                      // fixed by the reference problem
  const int N = in_sizes[0] / (B * 3);  // 8192
  const int M = in_sizes[1] / (B * 3);  // 8192

  const size_t Npad = pad512((size_t)N), Mpad = pad512((size_t)M);
  char* frags = (char*)d_ws;            // needs B*(Npad+Mpad)*32 = 4 MB here

  const size_t pmax = Npad > Mpad ? Npad : Mpad;
  dim3 g1((unsigned)(pmax / 256), 1, 2 * B);
  frag_kernel<<<g1, dim3(256), 0, stream>>>(xyz1, xyz2, frags, B, N, M);

  const int nmax = N > M ? N : M;
  dim3 g2((unsigned)((nmax + 255) / 256), 1, 2 * B);
  chamfer_mfma<<<g2, dim3(256), 0, stream>>>(xyz1, xyz2, frags, out, B, N, M);
}

// Round 2
// 94.775 us; speedup vs baseline: 1.3799x; 1.0492x over previous
//
#include <hip/hip_runtime.h>
#include <math.h>

// Chamfer distance via MFMA on MI355X (gfx950).
// B=8, N=M=8192, fp32 in/out. out = concat(dist1[B*N], dist2[B*M]).
//
// d(q,c) = |q|^2 + (|c|^2 - 2 q.c). The parenthesized part is computed as a
// K<=16 dot product on v_mfma_f32_32x32x16_bf16 using split-bf16 (hi+lo)
// operands; all four cross terms kept, plus |c|^2 embedded hi/lo against 1.0.
// bf16 x bf16 products are exact in the f32 accumulator.
//
// Round 2 change (occupancy): the query axis only yields 2048 waves
// (2/SIMD) at 64 queries/wave, which left the kernel latency-bound
// (MfmaUtil 31%, Occupancy 18%, no pipe saturated). Candidates are now
// split in half across blockIdx.y -> 4096 waves (4/SIMD) with the
// ds_read:MFMA ratio unchanged (each A-fragment feeds 2 MFMAs, keeping the
// LDS pipe under the MFMA pipe). Partial minima from the two halves merge
// via uint atomicMin (valid for non-negative floats); out is pre-memset to
// 0x7f7f7f7f each call.

typedef __attribute__((ext_vector_type(8))) short short8;
typedef __attribute__((ext_vector_type(16))) float f32x16;

#define CTC    512               // candidates per LDS tile
#define TILEB  (CTC * 32)        // 16 KB (CTC/32 groups x 1024 B)
#define NGRP   (CTC / 32)        // 16 groups per tile
#define NSPLIT 2                 // candidate halves (blockIdx.y)

__host__ __device__ static inline size_t pad512(size_t x) {
  return (x + 511) & ~(size_t)511;
}

__device__ __forceinline__ unsigned short bf16h(float x) {
  unsigned u = __float_as_uint(x);
  return (unsigned short)((u + 0x7fffu + ((u >> 16) & 1u)) >> 16);  // RNE
}
__device__ __forceinline__ float bf16f(unsigned short h) {
  return __uint_as_float((unsigned)h << 16);
}
__device__ __forceinline__ float m3(float a, float b, float c) {
  return fminf(fminf(a, b), c);  // -> v_min3_f32
}
__device__ __forceinline__ float red16(const f32x16& d, float mm) {
  float r0 = m3(d[0], d[1], d[2]);
  float r1 = m3(d[3], d[4], d[5]);
  float r2 = m3(d[6], d[7], d[8]);
  float r3 = m3(d[9], d[10], d[11]);
  float r4 = m3(d[12], d[13], d[14]);
  return m3(m3(r0, r1, r2), m3(r3, r4, d[15]), mm);   // 8 x v_min3 total
}

#define GLOAD_LDS16(gp, sp)                                                   \
  __builtin_amdgcn_global_load_lds(                                           \
      (const __attribute__((address_space(1))) unsigned int*)(gp),            \
      (__attribute__((address_space(3))) unsigned int*)(sp), 16, 0, 0)

// ---------------------------------------------------------------------------
// Kernel 1: transform candidate points into A-fragment layout.
// Per candidate j (group g=j>>5, row r=j&31), two 16B fragments:
//   khalf0: [Eh.x,Eh.y,Eh.z, El.x,El.y,El.z, Eh.x,Eh.y]
//   khalf1: [Eh.z, El.x,El.y,El.z, sqh, sql, 0, 0]       (E = -2c, sq = |c|^2)
// stored at frag16[g*64 + h*32 + r] == consumer byte addr g*1024 + lane*16
// with lane = h*32 + r.
// ---------------------------------------------------------------------------
__global__ __launch_bounds__(256) void frag_kernel(
    const float* __restrict__ xyz1, const float* __restrict__ xyz2,
    char* __restrict__ frags, int B, int N, int M)
{
  const int z = blockIdx.z, dir = z / B, b = z % B;
  const size_t Mpad = pad512((size_t)M), Npad = pad512((size_t)N);
  const float* cp; char* reg_; int Nc; size_t Pc;
  if (dir == 0) {  // candidates = xyz2
    cp = xyz2 + (size_t)b * M * 3;
    reg_ = frags + (size_t)b * Mpad * 32;
    Nc = M; Pc = Mpad;
  } else {         // candidates = xyz1
    cp = xyz1 + (size_t)b * N * 3;
    reg_ = frags + (size_t)B * Mpad * 32 + (size_t)b * Npad * 32;
    Nc = N; Pc = Npad;
  }
  const size_t j = (size_t)blockIdx.x * 256 + threadIdx.x;
  if (j >= Pc) return;

  float x = 0.f, y = 0.f, zz = 0.f, sq = 3.0e38f;   // pad -> "infinitely far"
  if (j < (size_t)Nc) {
    x = cp[3 * j + 0]; y = cp[3 * j + 1]; zz = cp[3 * j + 2];
    sq = x * x; sq = fmaf(y, y, sq); sq = fmaf(zz, zz, sq);
  }
  const float ex = -2.f * x, ey = -2.f * y, ez = -2.f * zz;
  const unsigned short ehx = bf16h(ex); const unsigned short elx = bf16h(ex - bf16f(ehx));
  const unsigned short ehy = bf16h(ey); const unsigned short ely = bf16h(ey - bf16f(ehy));
  const unsigned short ehz = bf16h(ez); const unsigned short elz = bf16h(ez - bf16f(ehz));
  const unsigned short sh  = bf16h(sq); const unsigned short sl  = bf16h(sq - bf16f(sh));

  short8 f0, f1;
  f0[0] = (short)ehx; f0[1] = (short)ehy; f0[2] = (short)ehz; f0[3] = (short)elx;
  f0[4] = (short)ely; f0[5] = (short)elz; f0[6] = (short)ehx; f0[7] = (short)ehy;
  f1[0] = (short)ehz; f1[1] = (short)elx; f1[2] = (short)ely; f1[3] = (short)elz;
  f1[4] = (short)sh;  f1[5] = (short)sl;  f1[6] = 0;          f1[7] = 0;

  short8* fp = (short8*)reg_ + ((j >> 5) * 64 + (j & 31));
  fp[0]  = f0;    // khalf 0
  fp[32] = f1;    // khalf 1
}

// Query B-fragment (pairs slot-for-slot with the candidate fragment):
//   khalf0: [Qh.x,Qh.y,Qh.z, Qh.x,Qh.y,Qh.z, Ql.x,Ql.y]
//   khalf1: [Ql.z, Ql.x,Ql.y,Ql.z, 1.0, 1.0, 0, 0]
// Slot products sum to  q.(-2c) + |c|^2  exactly as packed.
__device__ __forceinline__ short8 make_qfrag(float x, float y, float z, int hi) {
  const unsigned short hx = bf16h(x); const unsigned short lx = bf16h(x - bf16f(hx));
  const unsigned short hy = bf16h(y); const unsigned short ly = bf16h(y - bf16f(hy));
  const unsigned short hz = bf16h(z); const unsigned short lz = bf16h(z - bf16f(hz));
  const unsigned short ONE = 0x3F80;
  short8 f;
  if (hi == 0) {
    f[0] = (short)hx; f[1] = (short)hy; f[2] = (short)hz; f[3] = (short)hx;
    f[4] = (short)hy; f[5] = (short)hz; f[6] = (short)lx; f[7] = (short)ly;
  } else {
    f[0] = (short)lz; f[1] = (short)lx; f[2] = (short)ly; f[3] = (short)lz;
    f[4] = (short)ONE; f[5] = (short)ONE; f[6] = 0; f[7] = 0;
  }
  return f;
}

// ---------------------------------------------------------------------------
// Kernel 2: 256 threads (4 waves). Each wave owns 64 queries (2 B-frags).
// blockIdx.y selects a candidate half; block scans its half in
// double-buffered 16KB LDS tiles. Per group: 1 ds_read_b128 -> 2 MFMA ->
// 2x8 v_min3. Partial minima merge via uint atomicMin.
// ---------------------------------------------------------------------------
__global__ __launch_bounds__(256, 4) void chamfer_mfma(
    const float* __restrict__ xyz1, const float* __restrict__ xyz2,
    const char* __restrict__ frags, float* __restrict__ out,
    int B, int N, int M)
{
  const int z = blockIdx.z, dir = z / B, b = z % B;
  const size_t Mpad = pad512((size_t)M), Npad = pad512((size_t)N);
  const float* qp; float* o; const char* fr; int Nq, Nc;
  if (dir == 0) {   // queries = xyz1, candidates = xyz2
    qp = xyz1 + (size_t)b * N * 3;
    o  = out + (size_t)b * N;
    fr = frags + (size_t)b * Mpad * 32;
    Nq = N; Nc = (int)Mpad;
  } else {          // queries = xyz2, candidates = xyz1
    qp = xyz2 + (size_t)b * M * 3;
    o  = out + (size_t)B * N + (size_t)b * M;
    fr = frags + (size_t)B * Mpad * 32 + (size_t)b * Npad * 32;
    Nq = M; Nc = (int)Npad;
  }
  if ((int)(blockIdx.x * 256) >= Nq) return;   // block-uniform early out

  // ---- candidate half for this block ----
  const int ntT = Nc / CTC;                 // total tiles
  const int hT  = (ntT + NSPLIT - 1) / NSPLIT;
  const int t0  = blockIdx.y * hT;
  const int t1  = (t0 + hT < ntT) ? (t0 + hT) : ntT;
  const int nt  = t1 - t0;                  // tiles this block scans
  if (nt <= 0) return;
  const char* frh = fr + (size_t)t0 * TILEB;

  const int lane = threadIdx.x & 63;
  const int wid  = threadIdx.x >> 6;
  const int hi   = lane >> 5;

  // ---- two query sets per wave ----
  const int qbase = blockIdx.x * 256 + wid * 64;
  const int n0 = qbase + (lane & 31);
  const int n1 = n0 + 32;
  const int n0c = n0 < Nq ? n0 : Nq - 1;
  const int n1c = n1 < Nq ? n1 : Nq - 1;
  const float q0x = qp[3 * n0c], q0y = qp[3 * n0c + 1], q0z = qp[3 * n0c + 2];
  const float q1x = qp[3 * n1c], q1y = qp[3 * n1c + 1], q1z = qp[3 * n1c + 2];
  float sqq0 = q0x * q0x; sqq0 = fmaf(q0y, q0y, sqq0); sqq0 = fmaf(q0z, q0z, sqq0);
  float sqq1 = q1x * q1x; sqq1 = fmaf(q1y, q1y, sqq1); sqq1 = fmaf(q1z, q1z, sqq1);
  const short8 bq0 = make_qfrag(q0x, q0y, q0z, hi);
  const short8 bq1 = make_qfrag(q1x, q1y, q1z, hi);

  __shared__ __align__(16) char lds[2][TILEB];

  // stage tile 0 into buffer 0 (each wave covers 4 x 1KB slices)
  {
    const char* src = frh + wid * 1024 + lane * 16;
    char* dst = lds[0] + wid * 1024;
#pragma unroll
    for (int i = 0; i < 4; ++i)
      GLOAD_LDS16(src + i * 4096, dst + i * 4096);
  }

  f32x16 zacc = {0.f,0.f,0.f,0.f,0.f,0.f,0.f,0.f,0.f,0.f,0.f,0.f,0.f,0.f,0.f,0.f};
  float mm0 = 3.0e38f, mm1 = 3.0e38f;

  for (int t = 0; t < nt; ++t) {
    asm volatile("s_waitcnt vmcnt(0)" ::: "memory");
    __syncthreads();   // tile t staged & visible; buf t^1 free for next stage
    if (t + 1 < nt) {
      const char* src = frh + (size_t)(t + 1) * TILEB + wid * 1024 + lane * 16;
      char* dst = lds[(t + 1) & 1] + wid * 1024;
#pragma unroll
      for (int i = 0; i < 4; ++i)
        GLOAD_LDS16(src + i * 4096, dst + i * 4096);
    }
    const char* bc = lds[t & 1] + lane * 16;   // per-lane-contiguous: no bank conflicts
#pragma unroll 4
    for (int g = 0; g < NGRP; ++g) {
      const short8 fa = *(const short8*)(bc + g * 1024);
      const f32x16 da = __builtin_amdgcn_mfma_f32_32x32x16_bf16(fa, bq0, zacc, 0, 0, 0);
      const f32x16 db = __builtin_amdgcn_mfma_f32_32x32x16_bf16(fa, bq1, zacc, 0, 0, 0);
      mm0 = red16(da, mm0);
      mm1 = red16(db, mm1);
    }
  }

  // C layout (m74/m101): col = lane&31 (query), rows split across lane^32.
  mm0 = fminf(mm0, __shfl_xor(mm0, 32));
  mm1 = fminf(mm1, __shfl_xor(mm1, 32));
  if (lane < 32) {
    if (n0 < Nq) atomicMin((unsigned int*)(o + n0), __float_as_uint(fmaxf(mm0 + sqq0, 0.f)));
    if (n1 < Nq) atomicMin((unsigned int*)(o + n1), __float_as_uint(fmaxf(mm1 + sqq1, 0.f)));
  }
}

extern "C" void kernel_launch(void* const* d_in, const int* in_sizes, int n_in,
                              void* d_out, int out_size, void* d_ws, size_t ws_size,
                              hipStream_t stream) {
  const float* xyz1 = (const float*)d_in[0];
  const float* xyz2 = (const float*)d_in[1];
  float* out = (float*)d_out;

  const int B = 8;                      // fixed by the reference problem
  const int N = in_sizes[0] / (B * 3);  // 8192
  const int M = in_sizes[1] / (B * 3);  // 8192

  // Outputs to huge positive float (0x7f7f7f7f) so uint atomicMin of
  // non-negative distances always wins.
  hipMemsetAsync(d_out, 0x7f, (size_t)out_size * sizeof(float), stream);

  const size_t Npad = pad512((size_t)N), Mpad = pad512((size_t)M);
  char* frags = (char*)d_ws;            // needs B*(Npad+Mpad)*32 = 4 MB here

  const size_t pmax = Npad > Mpad ? Npad : Mpad;
  dim3 g1((unsigned)(pmax / 256), 1, 2 * B);
  frag_kernel<<<g1, dim3(256), 0, stream>>>(xyz1, xyz2, frags, B, N, M);

  const int nmax = N > M ? N : M;
  dim3 g2((unsigned)((nmax + 255) / 256), NSPLIT, 2 * B);
  chamfer_mfma<<<g2, dim3(256), 0, stream>>>(xyz1, xyz2, frags, out, B, N, M);
}

// Round 3
// 94.220 us; speedup vs baseline: 1.3881x; 1.0059x over previous
//
#include <hip/hip_runtime.h>
#include <math.h>

// Chamfer distance via MFMA on MI355X (gfx950).
// B=8, N=M=8192, fp32 in/out. out = concat(dist1[B*N], dist2[B*M]).
//
// d(q,c) = |q|^2 + (|c|^2 - 2 q.c). The parenthesized part is computed as a
// K<=16 dot product on v_mfma_f32_32x32x16_bf16 using split-bf16 (hi+lo)
// operands; all four cross terms kept, plus |c|^2 embedded hi/lo against 1.0.
// bf16 x bf16 products are exact in the f32 accumulator.
//
// Round 3 change (occupancy, again): round 2's NSPLIT=2 gave 4 waves/SIMD but
// 32 KB LDS/block capped residency at 4 blocks/CU and the per-tile
// vmcnt(0)+barrier convoy had little cross-block overlap (MfmaUtil ~45%).
// Now: CTC 512->256 (16 KB LDS/block double-buffered) + NSPLIT=4
// -> 2048 blocks = 8 blocks/CU = 8 waves/SIMD (hw max at <=64 VGPR;
// __launch_bounds__(256,8), measured VGPR=44). ds_read:MFMA ratio unchanged
// (each A-fragment feeds 2 MFMAs; LDS pipe stays under the MFMA pipe).
// Partial minima merge via uint atomicMin (valid for non-negative floats);
// out pre-memset to 0x7f7f7f7f each call.
//
// NOTE (profiling): the 43 us __amd_rocclr_fillBufferAligned dispatches in
// rocprof are the harness's 256 MiB workspace poison, present every
// iteration regardless of kernel content — fixed overhead we can't remove.

typedef __attribute__((ext_vector_type(8))) short short8;
typedef __attribute__((ext_vector_type(16))) float f32x16;

#define CTC    256               // candidates per LDS tile
#define TILEB  (CTC * 32)        // 8 KB (CTC/32 groups x 1024 B)
#define NGRP   (CTC / 32)        // 8 groups per tile
#define NSPLIT 4                 // candidate quarters (blockIdx.y)

__host__ __device__ static inline size_t pad512(size_t x) {
  return (x + 511) & ~(size_t)511;
}

__device__ __forceinline__ unsigned short bf16h(float x) {
  unsigned u = __float_as_uint(x);
  return (unsigned short)((u + 0x7fffu + ((u >> 16) & 1u)) >> 16);  // RNE
}
__device__ __forceinline__ float bf16f(unsigned short h) {
  return __uint_as_float((unsigned)h << 16);
}
__device__ __forceinline__ float m3(float a, float b, float c) {
  return fminf(fminf(a, b), c);  // -> v_min3_f32
}
__device__ __forceinline__ float red16(const f32x16& d, float mm) {
  float r0 = m3(d[0], d[1], d[2]);
  float r1 = m3(d[3], d[4], d[5]);
  float r2 = m3(d[6], d[7], d[8]);
  float r3 = m3(d[9], d[10], d[11]);
  float r4 = m3(d[12], d[13], d[14]);
  return m3(m3(r0, r1, r2), m3(r3, r4, d[15]), mm);   // 8 x v_min3 total
}

#define GLOAD_LDS16(gp, sp)                                                   \
  __builtin_amdgcn_global_load_lds(                                           \
      (const __attribute__((address_space(1))) unsigned int*)(gp),            \
      (__attribute__((address_space(3))) unsigned int*)(sp), 16, 0, 0)

// ---------------------------------------------------------------------------
// Kernel 1: transform candidate points into A-fragment layout.
// Per candidate j (group g=j>>5, row r=j&31), two 16B fragments:
//   khalf0: [Eh.x,Eh.y,Eh.z, El.x,El.y,El.z, Eh.x,Eh.y]
//   khalf1: [Eh.z, El.x,El.y,El.z, sqh, sql, 0, 0]       (E = -2c, sq = |c|^2)
// stored at frag16[g*64 + h*32 + r] == consumer byte addr g*1024 + lane*16
// with lane = h*32 + r.
// ---------------------------------------------------------------------------
__global__ __launch_bounds__(256) void frag_kernel(
    const float* __restrict__ xyz1, const float* __restrict__ xyz2,
    char* __restrict__ frags, int B, int N, int M)
{
  const int z = blockIdx.z, dir = z / B, b = z % B;
  const size_t Mpad = pad512((size_t)M), Npad = pad512((size_t)N);
  const float* cp; char* reg_; int Nc; size_t Pc;
  if (dir == 0) {  // candidates = xyz2
    cp = xyz2 + (size_t)b * M * 3;
    reg_ = frags + (size_t)b * Mpad * 32;
    Nc = M; Pc = Mpad;
  } else {         // candidates = xyz1
    cp = xyz1 + (size_t)b * N * 3;
    reg_ = frags + (size_t)B * Mpad * 32 + (size_t)b * Npad * 32;
    Nc = N; Pc = Npad;
  }
  const size_t j = (size_t)blockIdx.x * 256 + threadIdx.x;
  if (j >= Pc) return;

  float x = 0.f, y = 0.f, zz = 0.f, sq = 3.0e38f;   // pad -> "infinitely far"
  if (j < (size_t)Nc) {
    x = cp[3 * j + 0]; y = cp[3 * j + 1]; zz = cp[3 * j + 2];
    sq = x * x; sq = fmaf(y, y, sq); sq = fmaf(zz, zz, sq);
  }
  const float ex = -2.f * x, ey = -2.f * y, ez = -2.f * zz;
  const unsigned short ehx = bf16h(ex); const unsigned short elx = bf16h(ex - bf16f(ehx));
  const unsigned short ehy = bf16h(ey); const unsigned short ely = bf16h(ey - bf16f(ehy));
  const unsigned short ehz = bf16h(ez); const unsigned short elz = bf16h(ez - bf16f(ehz));
  const unsigned short sh  = bf16h(sq); const unsigned short sl  = bf16h(sq - bf16f(sh));

  short8 f0, f1;
  f0[0] = (short)ehx; f0[1] = (short)ehy; f0[2] = (short)ehz; f0[3] = (short)elx;
  f0[4] = (short)ely; f0[5] = (short)elz; f0[6] = (short)ehx; f0[7] = (short)ehy;
  f1[0] = (short)ehz; f1[1] = (short)elx; f1[2] = (short)ely; f1[3] = (short)elz;
  f1[4] = (short)sh;  f1[5] = (short)sl;  f1[6] = 0;          f1[7] = 0;

  short8* fp = (short8*)reg_ + ((j >> 5) * 64 + (j & 31));
  fp[0]  = f0;    // khalf 0
  fp[32] = f1;    // khalf 1
}

// Query B-fragment (pairs slot-for-slot with the candidate fragment):
//   khalf0: [Qh.x,Qh.y,Qh.z, Qh.x,Qh.y,Qh.z, Ql.x,Ql.y]
//   khalf1: [Ql.z, Ql.x,Ql.y,Ql.z, 1.0, 1.0, 0, 0]
// Slot products sum to  q.(-2c) + |c|^2  exactly as packed.
__device__ __forceinline__ short8 make_qfrag(float x, float y, float z, int hi) {
  const unsigned short hx = bf16h(x); const unsigned short lx = bf16h(x - bf16f(hx));
  const unsigned short hy = bf16h(y); const unsigned short ly = bf16h(y - bf16f(hy));
  const unsigned short hz = bf16h(z); const unsigned short lz = bf16h(z - bf16f(hz));
  const unsigned short ONE = 0x3F80;
  short8 f;
  if (hi == 0) {
    f[0] = (short)hx; f[1] = (short)hy; f[2] = (short)hz; f[3] = (short)hx;
    f[4] = (short)hy; f[5] = (short)hz; f[6] = (short)lx; f[7] = (short)ly;
  } else {
    f[0] = (short)lz; f[1] = (short)lx; f[2] = (short)ly; f[3] = (short)lz;
    f[4] = (short)ONE; f[5] = (short)ONE; f[6] = 0; f[7] = 0;
  }
  return f;
}

// ---------------------------------------------------------------------------
// Kernel 2: 256 threads (4 waves). Each wave owns 64 queries (2 B-frags).
// blockIdx.y selects a candidate quarter; block scans it in double-buffered
// 8KB LDS tiles. Per group: 1 ds_read_b128 -> 2 MFMA -> 2x8 v_min3.
// Partial minima merge via uint atomicMin.
// ---------------------------------------------------------------------------
__global__ __launch_bounds__(256, 8) void chamfer_mfma(
    const float* __restrict__ xyz1, const float* __restrict__ xyz2,
    const char* __restrict__ frags, float* __restrict__ out,
    int B, int N, int M)
{
  const int z = blockIdx.z, dir = z / B, b = z % B;
  const size_t Mpad = pad512((size_t)M), Npad = pad512((size_t)N);
  const float* qp; float* o; const char* fr; int Nq, Nc;
  if (dir == 0) {   // queries = xyz1, candidates = xyz2
    qp = xyz1 + (size_t)b * N * 3;
    o  = out + (size_t)b * N;
    fr = frags + (size_t)b * Mpad * 32;
    Nq = N; Nc = (int)Mpad;
  } else {          // queries = xyz2, candidates = xyz1
    qp = xyz2 + (size_t)b * M * 3;
    o  = out + (size_t)B * N + (size_t)b * M;
    fr = frags + (size_t)B * Mpad * 32 + (size_t)b * Npad * 32;
    Nq = M; Nc = (int)Npad;
  }
  if ((int)(blockIdx.x * 256) >= Nq) return;   // block-uniform early out

  // ---- candidate quarter for this block ----
  const int ntT = Nc / CTC;                 // total tiles
  const int hT  = (ntT + NSPLIT - 1) / NSPLIT;
  const int t0  = blockIdx.y * hT;
  const int t1  = (t0 + hT < ntT) ? (t0 + hT) : ntT;
  const int nt  = t1 - t0;                  // tiles this block scans
  if (nt <= 0) return;
  const char* frh = fr + (size_t)t0 * TILEB;

  const int lane = threadIdx.x & 63;
  const int wid  = threadIdx.x >> 6;
  const int hi   = lane >> 5;

  // ---- two query sets per wave ----
  const int qbase = blockIdx.x * 256 + wid * 64;
  const int n0 = qbase + (lane & 31);
  const int n1 = n0 + 32;
  const int n0c = n0 < Nq ? n0 : Nq - 1;
  const int n1c = n1 < Nq ? n1 : Nq - 1;
  const float q0x = qp[3 * n0c], q0y = qp[3 * n0c + 1], q0z = qp[3 * n0c + 2];
  const float q1x = qp[3 * n1c], q1y = qp[3 * n1c + 1], q1z = qp[3 * n1c + 2];
  float sqq0 = q0x * q0x; sqq0 = fmaf(q0y, q0y, sqq0); sqq0 = fmaf(q0z, q0z, sqq0);
  float sqq1 = q1x * q1x; sqq1 = fmaf(q1y, q1y, sqq1); sqq1 = fmaf(q1z, q1z, sqq1);
  const short8 bq0 = make_qfrag(q0x, q0y, q0z, hi);
  const short8 bq1 = make_qfrag(q1x, q1y, q1z, hi);

  __shared__ __align__(16) char lds[2][TILEB];

  // stage tile 0 into buffer 0 (each wave covers 2 x 1KB slices)
  {
    const char* src = frh + wid * 1024 + lane * 16;
    char* dst = lds[0] + wid * 1024;
#pragma unroll
    for (int i = 0; i < 2; ++i)
      GLOAD_LDS16(src + i * 4096, dst + i * 4096);
  }

  f32x16 zacc = {0.f,0.f,0.f,0.f,0.f,0.f,0.f,0.f,0.f,0.f,0.f,0.f,0.f,0.f,0.f,0.f};
  float mm0 = 3.0e38f, mm1 = 3.0e38f;

  for (int t = 0; t < nt; ++t) {
    asm volatile("s_waitcnt vmcnt(0)" ::: "memory");
    __syncthreads();   // tile t staged & visible; buf t^1 free for next stage
    if (t + 1 < nt) {
      const char* src = frh + (size_t)(t + 1) * TILEB + wid * 1024 + lane * 16;
      char* dst = lds[(t + 1) & 1] + wid * 1024;
#pragma unroll
      for (int i = 0; i < 2; ++i)
        GLOAD_LDS16(src + i * 4096, dst + i * 4096);
    }
    const char* bc = lds[t & 1] + lane * 16;   // per-lane-contiguous: no bank conflicts
#pragma unroll 4
    for (int g = 0; g < NGRP; ++g) {
      const short8 fa = *(const short8*)(bc + g * 1024);
      const f32x16 da = __builtin_amdgcn_mfma_f32_32x32x16_bf16(fa, bq0, zacc, 0, 0, 0);
      const f32x16 db = __builtin_amdgcn_mfma_f32_32x32x16_bf16(fa, bq1, zacc, 0, 0, 0);
      mm0 = red16(da, mm0);
      mm1 = red16(db, mm1);
    }
  }

  // C layout (m74/m101): col = lane&31 (query), rows split across lane^32.
  mm0 = fminf(mm0, __shfl_xor(mm0, 32));
  mm1 = fminf(mm1, __shfl_xor(mm1, 32));
  if (lane < 32) {
    if (n0 < Nq) atomicMin((unsigned int*)(o + n0), __float_as_uint(fmaxf(mm0 + sqq0, 0.f)));
    if (n1 < Nq) atomicMin((unsigned int*)(o + n1), __float_as_uint(fmaxf(mm1 + sqq1, 0.f)));
  }
}

extern "C" void kernel_launch(void* const* d_in, const int* in_sizes, int n_in,
                              void* d_out, int out_size, void* d_ws, size_t ws_size,
                              hipStream_t stream) {
  const float* xyz1 = (const float*)d_in[0];
  const float* xyz2 = (const float*)d_in[1];
  float* out = (float*)d_out;

  const int B = 8;                      // fixed by the reference problem
  const int N = in_sizes[0] / (B * 3);  // 8192
  const int M = in_sizes[1] / (B * 3);  // 8192

  // Outputs to huge positive float (0x7f7f7f7f) so uint atomicMin of
  // non-negative distances always wins.
  hipMemsetAsync(d_out, 0x7f, (size_t)out_size * sizeof(float), stream);

  const size_t Npad = pad512((size_t)N), Mpad = pad512((size_t)M);
  char* frags = (char*)d_ws;            // needs B*(Npad+Mpad)*32 = 4 MB here

  const size_t pmax = Npad > Mpad ? Npad : Mpad;
  dim3 g1((unsigned)(pmax / 256), 1, 2 * B);
  frag_kernel<<<g1, dim3(256), 0, stream>>>(xyz1, xyz2, frags, B, N, M);

  const int nmax = N > M ? N : M;
  dim3 g2((unsigned)((nmax + 255) / 256), NSPLIT, 2 * B);
  chamfer_mfma<<<g2, dim3(256), 0, stream>>>(xyz1, xyz2, frags, out, B, N, M);
}

// Round 4
// 92.779 us; speedup vs baseline: 1.4096x; 1.0155x over previous
//
#include <hip/hip_runtime.h>
#include <math.h>

// Chamfer distance via MFMA on MI355X (gfx950).
// B=8, N=M=8192, fp32 in/out. out = concat(dist1[B*N], dist2[B*M]).
//
// d(q,c) = |q|^2 + (|c|^2 - 2 q.c). The parenthesized part is a K<=16 dot
// product on v_mfma_f32_32x32x16_bf16 with split-bf16 (hi+lo) operands; all
// four cross terms kept, plus |c|^2 embedded hi/lo against 1.0. bf16 x bf16
// products are exact in the f32 accumulator.
//
// Round 4 change (structure): rounds 2-3 proved the kernel is NOT
// occupancy-limited (2->4->8 waves/SIMD: 46 -> 41 -> 40 us). The cost is the
// per-tile vmcnt(0)+barrier convoy of the LDS double-buffer. The frag array
// is 4 MB = L2-resident, so LDS staging is pure overhead (guide common-
// mistake #7). Now each wave streams candidate fragments DIRECTLY
// global->register (lane-contiguous global_load_dwordx4, depth-2 register
// prefetch -> compiler-counted vmcnt), no barriers, no LDS, fully
// independent waves. 1D grid mapped so id%16 == z: same-z blocks land on
// the same XCD (round-robin %8), giving each XCD a ~512 KB frag working set
// in its private L2. s_setprio(1) around the MFMA pair (free-running waves
// = the role-diversity regime where setprio pays).
//
// NOTE (profiling): the 43 us __amd_rocclr_fillBufferAligned dispatches are
// the harness's 256 MiB workspace poison, fixed per-iteration overhead.

typedef __attribute__((ext_vector_type(8))) short short8;
typedef __attribute__((ext_vector_type(16))) float f32x16;

#define NSPLIT 4                 // candidate quarters per (z) scan

__host__ __device__ static inline size_t pad512(size_t x) {
  return (x + 511) & ~(size_t)511;
}

__device__ __forceinline__ unsigned short bf16h(float x) {
  unsigned u = __float_as_uint(x);
  return (unsigned short)((u + 0x7fffu + ((u >> 16) & 1u)) >> 16);  // RNE
}
__device__ __forceinline__ float bf16f(unsigned short h) {
  return __uint_as_float((unsigned)h << 16);
}
__device__ __forceinline__ float m3(float a, float b, float c) {
  return fminf(fminf(a, b), c);  // -> v_min3_f32
}
__device__ __forceinline__ float red16(const f32x16& d, float mm) {
  float r0 = m3(d[0], d[1], d[2]);
  float r1 = m3(d[3], d[4], d[5]);
  float r2 = m3(d[6], d[7], d[8]);
  float r3 = m3(d[9], d[10], d[11]);
  float r4 = m3(d[12], d[13], d[14]);
  return m3(m3(r0, r1, r2), m3(r3, r4, d[15]), mm);   // 8 x v_min3 total
}

// ---------------------------------------------------------------------------
// Kernel 1: transform candidate points into A-fragment layout.
// Per candidate j (group g=j>>5, row r=j&31), two 16B fragments:
//   khalf0: [Eh.x,Eh.y,Eh.z, El.x,El.y,El.z, Eh.x,Eh.y]
//   khalf1: [Eh.z, El.x,El.y,El.z, sqh, sql, 0, 0]       (E = -2c, sq = |c|^2)
// stored at frag16[g*64 + h*32 + r] == consumer byte addr g*1024 + lane*16
// with lane = h*32 + r.
// ---------------------------------------------------------------------------
__global__ __launch_bounds__(256) void frag_kernel(
    const float* __restrict__ xyz1, const float* __restrict__ xyz2,
    char* __restrict__ frags, int B, int N, int M)
{
  const int z = blockIdx.z, dir = z / B, b = z % B;
  const size_t Mpad = pad512((size_t)M), Npad = pad512((size_t)N);
  const float* cp; char* reg_; int Nc; size_t Pc;
  if (dir == 0) {  // candidates = xyz2
    cp = xyz2 + (size_t)b * M * 3;
    reg_ = frags + (size_t)b * Mpad * 32;
    Nc = M; Pc = Mpad;
  } else {         // candidates = xyz1
    cp = xyz1 + (size_t)b * N * 3;
    reg_ = frags + (size_t)B * Mpad * 32 + (size_t)b * Npad * 32;
    Nc = N; Pc = Npad;
  }
  const size_t j = (size_t)blockIdx.x * 256 + threadIdx.x;
  if (j >= Pc) return;

  float x = 0.f, y = 0.f, zz = 0.f, sq = 3.0e38f;   // pad -> "infinitely far"
  if (j < (size_t)Nc) {
    x = cp[3 * j + 0]; y = cp[3 * j + 1]; zz = cp[3 * j + 2];
    sq = x * x; sq = fmaf(y, y, sq); sq = fmaf(zz, zz, sq);
  }
  const float ex = -2.f * x, ey = -2.f * y, ez = -2.f * zz;
  const unsigned short ehx = bf16h(ex); const unsigned short elx = bf16h(ex - bf16f(ehx));
  const unsigned short ehy = bf16h(ey); const unsigned short ely = bf16h(ey - bf16f(ehy));
  const unsigned short ehz = bf16h(ez); const unsigned short elz = bf16h(ez - bf16f(ehz));
  const unsigned short sh  = bf16h(sq); const unsigned short sl  = bf16h(sq - bf16f(sh));

  short8 f0, f1;
  f0[0] = (short)ehx; f0[1] = (short)ehy; f0[2] = (short)ehz; f0[3] = (short)elx;
  f0[4] = (short)ely; f0[5] = (short)elz; f0[6] = (short)ehx; f0[7] = (short)ehy;
  f1[0] = (short)ehz; f1[1] = (short)elx; f1[2] = (short)ely; f1[3] = (short)elz;
  f1[4] = (short)sh;  f1[5] = (short)sl;  f1[6] = 0;          f1[7] = 0;

  short8* fp = (short8*)reg_ + ((j >> 5) * 64 + (j & 31));
  fp[0]  = f0;    // khalf 0
  fp[32] = f1;    // khalf 1
}

// Query B-fragment (pairs slot-for-slot with the candidate fragment):
//   khalf0: [Qh.x,Qh.y,Qh.z, Qh.x,Qh.y,Qh.z, Ql.x,Ql.y]
//   khalf1: [Ql.z, Ql.x,Ql.y,Ql.z, 1.0, 1.0, 0, 0]
// Slot products sum to  q.(-2c) + |c|^2  exactly as packed.
__device__ __forceinline__ short8 make_qfrag(float x, float y, float z, int hi) {
  const unsigned short hx = bf16h(x); const unsigned short lx = bf16h(x - bf16f(hx));
  const unsigned short hy = bf16h(y); const unsigned short ly = bf16h(y - bf16f(hy));
  const unsigned short hz = bf16h(z); const unsigned short lz = bf16h(z - bf16f(hz));
  const unsigned short ONE = 0x3F80;
  short8 f;
  if (hi == 0) {
    f[0] = (short)hx; f[1] = (short)hy; f[2] = (short)hz; f[3] = (short)hx;
    f[4] = (short)hy; f[5] = (short)hz; f[6] = (short)lx; f[7] = (short)ly;
  } else {
    f[0] = (short)lz; f[1] = (short)lx; f[2] = (short)ly; f[3] = (short)lz;
    f[4] = (short)ONE; f[5] = (short)ONE; f[6] = 0; f[7] = 0;
  }
  return f;
}

// ---------------------------------------------------------------------------
// Kernel 2: 256 threads (4 waves), no LDS, no barriers. Each wave owns 64
// queries (2 B-frags) and streams its candidate quarter global->register
// with depth-2 prefetch. Per group: 1 global_load_dwordx4 -> 2 MFMA ->
// 2x8 v_min3. Partial minima merge via uint atomicMin.
// Grid is 1D with id%(2B) == z so same-z blocks share an XCD's L2.
// ---------------------------------------------------------------------------
__global__ __launch_bounds__(256, 8) void chamfer_mfma(
    const float* __restrict__ xyz1, const float* __restrict__ xyz2,
    const char* __restrict__ frags, float* __restrict__ out,
    int B, int N, int M)
{
  const int id   = (int)blockIdx.x;
  const int z    = id % (2 * B);          // fastest -> XCD (%8) keyed by z
  const int rest = id / (2 * B);
  const int by   = rest % NSPLIT;
  const int bx   = rest / NSPLIT;

  const int dir = z / B, b = z % B;
  const size_t Mpad = pad512((size_t)M), Npad = pad512((size_t)N);
  const float* qp; float* o; const char* fr; int Nq, Nc;
  if (dir == 0) {   // queries = xyz1, candidates = xyz2
    qp = xyz1 + (size_t)b * N * 3;
    o  = out + (size_t)b * N;
    fr = frags + (size_t)b * Mpad * 32;
    Nq = N; Nc = (int)Mpad;
  } else {          // queries = xyz2, candidates = xyz1
    qp = xyz2 + (size_t)b * M * 3;
    o  = out + (size_t)B * N + (size_t)b * M;
    fr = frags + (size_t)B * Mpad * 32 + (size_t)b * Npad * 32;
    Nq = M; Nc = (int)Npad;
  }
  if (bx * 256 >= Nq) return;   // block-uniform early out

  const int lane = threadIdx.x & 63;
  const int wid  = threadIdx.x >> 6;
  const int hi   = lane >> 5;

  // ---- candidate quarter: gq groups of 32 (gq is a multiple of 4) ----
  const int gq = Nc / (32 * NSPLIT);
  const char* gp = fr + (size_t)by * gq * 1024 + (size_t)lane * 16;

  // ---- two query sets per wave ----
  const int qbase = bx * 256 + wid * 64;
  const int n0 = qbase + (lane & 31);
  const int n1 = n0 + 32;
  const int n0c = n0 < Nq ? n0 : Nq - 1;
  const int n1c = n1 < Nq ? n1 : Nq - 1;
  const float q0x = qp[3 * n0c], q0y = qp[3 * n0c + 1], q0z = qp[3 * n0c + 2];
  const float q1x = qp[3 * n1c], q1y = qp[3 * n1c + 1], q1z = qp[3 * n1c + 2];
  float sqq0 = q0x * q0x; sqq0 = fmaf(q0y, q0y, sqq0); sqq0 = fmaf(q0z, q0z, sqq0);
  float sqq1 = q1x * q1x; sqq1 = fmaf(q1y, q1y, sqq1); sqq1 = fmaf(q1z, q1z, sqq1);
  const short8 bq0 = make_qfrag(q0x, q0y, q0z, hi);
  const short8 bq1 = make_qfrag(q1x, q1y, q1z, hi);

  const f32x16 zacc = {0.f,0.f,0.f,0.f,0.f,0.f,0.f,0.f,
                       0.f,0.f,0.f,0.f,0.f,0.f,0.f,0.f};
  float mm0 = 3.0e38f, mm1 = 3.0e38f;

  // depth-2 register prefetch. Prefetch may run up to 2 KB past the quarter
  // (and, for the last quarter of the last z, past the 4 MB frag region) —
  // values are never consumed and the workspace is >=256 MB, so it's safe.
  short8 f0 = *(const short8*)(gp);
  short8 f1 = *(const short8*)(gp + 1024);
  for (int g = 0; g < gq; g += 2) {
    const short8 nf0 = *(const short8*)(gp + (size_t)(g + 2) * 1024);
    __builtin_amdgcn_s_setprio(1);
    const f32x16 da = __builtin_amdgcn_mfma_f32_32x32x16_bf16(f0, bq0, zacc, 0, 0, 0);
    const f32x16 db = __builtin_amdgcn_mfma_f32_32x32x16_bf16(f0, bq1, zacc, 0, 0, 0);
    __builtin_amdgcn_s_setprio(0);
    mm0 = red16(da, mm0);
    mm1 = red16(db, mm1);
    f0 = nf0;

    const short8 nf1 = *(const short8*)(gp + (size_t)(g + 3) * 1024);
    __builtin_amdgcn_s_setprio(1);
    const f32x16 dc = __builtin_amdgcn_mfma_f32_32x32x16_bf16(f1, bq0, zacc, 0, 0, 0);
    const f32x16 dd = __builtin_amdgcn_mfma_f32_32x32x16_bf16(f1, bq1, zacc, 0, 0, 0);
    __builtin_amdgcn_s_setprio(0);
    mm0 = red16(dc, mm0);
    mm1 = red16(dd, mm1);
    f1 = nf1;
  }

  // C layout (m74/m101): col = lane&31 (query), rows split across lane^32.
  mm0 = fminf(mm0, __shfl_xor(mm0, 32));
  mm1 = fminf(mm1, __shfl_xor(mm1, 32));
  if (lane < 32) {
    if (n0 < Nq) atomicMin((unsigned int*)(o + n0), __float_as_uint(fmaxf(mm0 + sqq0, 0.f)));
    if (n1 < Nq) atomicMin((unsigned int*)(o + n1), __float_as_uint(fmaxf(mm1 + sqq1, 0.f)));
  }
}

extern "C" void kernel_launch(void* const* d_in, const int* in_sizes, int n_in,
                              void* d_out, int out_size, void* d_ws, size_t ws_size,
                              hipStream_t stream) {
  const float* xyz1 = (const float*)d_in[0];
  const float* xyz2 = (const float*)d_in[1];
  float* out = (float*)d_out;

  const int B = 8;                      // fixed by the reference problem
  const int N = in_sizes[0] / (B * 3);  // 8192
  const int M = in_sizes[1] / (B * 3);  // 8192

  // Outputs to huge positive float (0x7f7f7f7f) so uint atomicMin of
  // non-negative distances always wins.
  hipMemsetAsync(d_out, 0x7f, (size_t)out_size * sizeof(float), stream);

  const size_t Npad = pad512((size_t)N), Mpad = pad512((size_t)M);
  char* frags = (char*)d_ws;            // needs B*(Npad+Mpad)*32 = 4 MB here

  const size_t pmax = Npad > Mpad ? Npad : Mpad;
  dim3 g1((unsigned)(pmax / 256), 1, 2 * B);
  frag_kernel<<<g1, dim3(256), 0, stream>>>(xyz1, xyz2, frags, B, N, M);

  const int nmax = N > M ? N : M;
  const unsigned nx = (unsigned)((nmax + 255) / 256);
  dim3 g2(nx * NSPLIT * 2 * B, 1, 1);   // id%(2B)==z -> same-z blocks share XCD
  chamfer_mfma<<<g2, dim3(256), 0, stream>>>(xyz1, xyz2, frags, out, B, N, M);
}

// Round 5
// 91.735 us; speedup vs baseline: 1.4257x; 1.0114x over previous
//
#include <hip/hip_runtime.h>
#include <math.h>

// Chamfer distance via MFMA on MI355X (gfx950).
// B=8, N=M=8192, fp32 in/out. out = concat(dist1[B*N], dist2[B*M]).
//
// d(q,c) = |q|^2 + (|c|^2 - 2 q.c). The parenthesized part is a K<=16 dot
// product on v_mfma_f32_32x32x16_bf16 with split-bf16 (hi+lo) operands; all
// four cross terms kept, plus |c|^2 embedded hi/lo against 1.0. bf16 x bf16
// products are exact in the f32 accumulator.
//
// Round 5 change (A-fragment reuse): round 4's wave-private candidate stream
// made VMEM a co-binding pipe (8192 waves x 64 KB = 512 MB of L2 traffic
// ~ 15 us/CU, same magnitude as the 13.8 us MFMA floor). Each wave now
// carries FOUR query B-fragments (128 queries) so every 1 KB A-fragment
// load feeds 4 MFMAs instead of 2: VMEM halves to 256 MB (~7.7 us), MFMA
// total unchanged -> MFMA is the sole dominant pipe. 4096 waves = 4/SIMD
// (rounds 2-3 proved >4 buys nothing for this kernel). Depth-2 register
// prefetch covers L2 latency. Partial minima merge via uint atomicMin
// (valid for non-negative floats); out pre-memset to 0x7f7f7f7f.
//
// NOTE (profiling): the ~40 us __amd_rocclr_fillBufferAligned dispatches are
// the harness's 256 MiB workspace poison, fixed per-iteration overhead.

typedef __attribute__((ext_vector_type(8))) short short8;
typedef __attribute__((ext_vector_type(16))) float f32x16;

#define NSPLIT 4                 // candidate quarters per (z) scan
#define QPW    128               // queries per wave (4 B-fragments)
#define QPB    (QPW * 4)         // queries per block (4 waves)

__host__ __device__ static inline size_t pad512(size_t x) {
  return (x + 511) & ~(size_t)511;
}

__device__ __forceinline__ unsigned short bf16h(float x) {
  unsigned u = __float_as_uint(x);
  return (unsigned short)((u + 0x7fffu + ((u >> 16) & 1u)) >> 16);  // RNE
}
__device__ __forceinline__ float bf16f(unsigned short h) {
  return __uint_as_float((unsigned)h << 16);
}
__device__ __forceinline__ float m3(float a, float b, float c) {
  return fminf(fminf(a, b), c);  // -> v_min3_f32
}
__device__ __forceinline__ float red16(const f32x16& d, float mm) {
  float r0 = m3(d[0], d[1], d[2]);
  float r1 = m3(d[3], d[4], d[5]);
  float r2 = m3(d[6], d[7], d[8]);
  float r3 = m3(d[9], d[10], d[11]);
  float r4 = m3(d[12], d[13], d[14]);
  return m3(m3(r0, r1, r2), m3(r3, r4, d[15]), mm);   // 8 x v_min3 total
}

// ---------------------------------------------------------------------------
// Kernel 1: transform candidate points into A-fragment layout.
// Per candidate j (group g=j>>5, row r=j&31), two 16B fragments:
//   khalf0: [Eh.x,Eh.y,Eh.z, El.x,El.y,El.z, Eh.x,Eh.y]
//   khalf1: [Eh.z, El.x,El.y,El.z, sqh, sql, 0, 0]       (E = -2c, sq = |c|^2)
// stored at frag16[g*64 + h*32 + r] == consumer byte addr g*1024 + lane*16
// with lane = h*32 + r.
// ---------------------------------------------------------------------------
__global__ __launch_bounds__(256) void frag_kernel(
    const float* __restrict__ xyz1, const float* __restrict__ xyz2,
    char* __restrict__ frags, int B, int N, int M)
{
  const int z = blockIdx.z, dir = z / B, b = z % B;
  const size_t Mpad = pad512((size_t)M), Npad = pad512((size_t)N);
  const float* cp; char* reg_; int Nc; size_t Pc;
  if (dir == 0) {  // candidates = xyz2
    cp = xyz2 + (size_t)b * M * 3;
    reg_ = frags + (size_t)b * Mpad * 32;
    Nc = M; Pc = Mpad;
  } else {         // candidates = xyz1
    cp = xyz1 + (size_t)b * N * 3;
    reg_ = frags + (size_t)B * Mpad * 32 + (size_t)b * Npad * 32;
    Nc = N; Pc = Npad;
  }
  const size_t j = (size_t)blockIdx.x * 256 + threadIdx.x;
  if (j >= Pc) return;

  float x = 0.f, y = 0.f, zz = 0.f, sq = 3.0e38f;   // pad -> "infinitely far"
  if (j < (size_t)Nc) {
    x = cp[3 * j + 0]; y = cp[3 * j + 1]; zz = cp[3 * j + 2];
    sq = x * x; sq = fmaf(y, y, sq); sq = fmaf(zz, zz, sq);
  }
  const float ex = -2.f * x, ey = -2.f * y, ez = -2.f * zz;
  const unsigned short ehx = bf16h(ex); const unsigned short elx = bf16h(ex - bf16f(ehx));
  const unsigned short ehy = bf16h(ey); const unsigned short ely = bf16h(ey - bf16f(ehy));
  const unsigned short ehz = bf16h(ez); const unsigned short elz = bf16h(ez - bf16f(ehz));
  const unsigned short sh  = bf16h(sq); const unsigned short sl  = bf16h(sq - bf16f(sh));

  short8 f0, f1;
  f0[0] = (short)ehx; f0[1] = (short)ehy; f0[2] = (short)ehz; f0[3] = (short)elx;
  f0[4] = (short)ely; f0[5] = (short)elz; f0[6] = (short)ehx; f0[7] = (short)ehy;
  f1[0] = (short)ehz; f1[1] = (short)elx; f1[2] = (short)ely; f1[3] = (short)elz;
  f1[4] = (short)sh;  f1[5] = (short)sl;  f1[6] = 0;          f1[7] = 0;

  short8* fp = (short8*)reg_ + ((j >> 5) * 64 + (j & 31));
  fp[0]  = f0;    // khalf 0
  fp[32] = f1;    // khalf 1
}

// Query B-fragment (pairs slot-for-slot with the candidate fragment):
//   khalf0: [Qh.x,Qh.y,Qh.z, Qh.x,Qh.y,Qh.z, Ql.x,Ql.y]
//   khalf1: [Ql.z, Ql.x,Ql.y,Ql.z, 1.0, 1.0, 0, 0]
// Slot products sum to  q.(-2c) + |c|^2  exactly as packed.
__device__ __forceinline__ short8 make_qfrag(float x, float y, float z, int hi) {
  const unsigned short hx = bf16h(x); const unsigned short lx = bf16h(x - bf16f(hx));
  const unsigned short hy = bf16h(y); const unsigned short ly = bf16h(y - bf16f(hy));
  const unsigned short hz = bf16h(z); const unsigned short lz = bf16h(z - bf16f(hz));
  const unsigned short ONE = 0x3F80;
  short8 f;
  if (hi == 0) {
    f[0] = (short)hx; f[1] = (short)hy; f[2] = (short)hz; f[3] = (short)hx;
    f[4] = (short)hy; f[5] = (short)hz; f[6] = (short)lx; f[7] = (short)ly;
  } else {
    f[0] = (short)lz; f[1] = (short)lx; f[2] = (short)ly; f[3] = (short)lz;
    f[4] = (short)ONE; f[5] = (short)ONE; f[6] = 0; f[7] = 0;
  }
  return f;
}

// ---------------------------------------------------------------------------
// Kernel 2: 256 threads (4 waves), no LDS, no barriers. Each wave owns 128
// queries (4 B-frags) and streams its candidate quarter global->register
// with depth-2 prefetch. Per group: 1 global_load_dwordx4 -> 4 MFMA ->
// 4x8 v_min3. Partial minima merge via uint atomicMin.
// Grid is 1D with id%(2B) == z so same-z blocks share an XCD's L2.
// ---------------------------------------------------------------------------
__global__ __launch_bounds__(256, 4) void chamfer_mfma(
    const float* __restrict__ xyz1, const float* __restrict__ xyz2,
    const char* __restrict__ frags, float* __restrict__ out,
    int B, int N, int M)
{
  const int id   = (int)blockIdx.x;
  const int z    = id % (2 * B);          // fastest -> XCD (%8) keyed by z
  const int rest = id / (2 * B);
  const int by   = rest % NSPLIT;
  const int bx   = rest / NSPLIT;

  const int dir = z / B, b = z % B;
  const size_t Mpad = pad512((size_t)M), Npad = pad512((size_t)N);
  const float* qp; float* o; const char* fr; int Nq, Nc;
  if (dir == 0) {   // queries = xyz1, candidates = xyz2
    qp = xyz1 + (size_t)b * N * 3;
    o  = out + (size_t)b * N;
    fr = frags + (size_t)b * Mpad * 32;
    Nq = N; Nc = (int)Mpad;
  } else {          // queries = xyz2, candidates = xyz1
    qp = xyz2 + (size_t)b * M * 3;
    o  = out + (size_t)B * N + (size_t)b * M;
    fr = frags + (size_t)B * Mpad * 32 + (size_t)b * Npad * 32;
    Nq = M; Nc = (int)Npad;
  }
  if (bx * QPB >= Nq) return;   // block-uniform early out

  const int lane = threadIdx.x & 63;
  const int wid  = threadIdx.x >> 6;
  const int hi   = lane >> 5;

  // ---- candidate quarter: gq groups of 32 (gq is a multiple of 4) ----
  const int gq = Nc / (32 * NSPLIT);
  const char* gp = fr + (size_t)by * gq * 1024 + (size_t)lane * 16;

  // ---- four query sets per wave ----
  const int qbase = bx * QPB + wid * QPW;
  const int n0 = qbase + (lane & 31);
  const int n1 = n0 + 32;
  const int n2 = n0 + 64;
  const int n3 = n0 + 96;
  const int n0c = n0 < Nq ? n0 : Nq - 1;
  const int n1c = n1 < Nq ? n1 : Nq - 1;
  const int n2c = n2 < Nq ? n2 : Nq - 1;
  const int n3c = n3 < Nq ? n3 : Nq - 1;
  const float q0x = qp[3 * n0c], q0y = qp[3 * n0c + 1], q0z = qp[3 * n0c + 2];
  const float q1x = qp[3 * n1c], q1y = qp[3 * n1c + 1], q1z = qp[3 * n1c + 2];
  const float q2x = qp[3 * n2c], q2y = qp[3 * n2c + 1], q2z = qp[3 * n2c + 2];
  const float q3x = qp[3 * n3c], q3y = qp[3 * n3c + 1], q3z = qp[3 * n3c + 2];
  float sqq0 = q0x * q0x; sqq0 = fmaf(q0y, q0y, sqq0); sqq0 = fmaf(q0z, q0z, sqq0);
  float sqq1 = q1x * q1x; sqq1 = fmaf(q1y, q1y, sqq1); sqq1 = fmaf(q1z, q1z, sqq1);
  float sqq2 = q2x * q2x; sqq2 = fmaf(q2y, q2y, sqq2); sqq2 = fmaf(q2z, q2z, sqq2);
  float sqq3 = q3x * q3x; sqq3 = fmaf(q3y, q3y, sqq3); sqq3 = fmaf(q3z, q3z, sqq3);
  const short8 bq0 = make_qfrag(q0x, q0y, q0z, hi);
  const short8 bq1 = make_qfrag(q1x, q1y, q1z, hi);
  const short8 bq2 = make_qfrag(q2x, q2y, q2z, hi);
  const short8 bq3 = make_qfrag(q3x, q3y, q3z, hi);

  const f32x16 zacc = {0.f,0.f,0.f,0.f,0.f,0.f,0.f,0.f,
                       0.f,0.f,0.f,0.f,0.f,0.f,0.f,0.f};
  float mm0 = 3.0e38f, mm1 = 3.0e38f, mm2 = 3.0e38f, mm3 = 3.0e38f;

  // depth-2 register prefetch. Prefetch may run up to 2 KB past the quarter
  // (and, for the last quarter of the last z, past the 4 MB frag region) —
  // values are never consumed and the workspace is >=256 MB, so it's safe.
  short8 f0 = *(const short8*)(gp);
  short8 f1 = *(const short8*)(gp + 1024);
  for (int g = 0; g < gq; g += 2) {
    const short8 nf0 = *(const short8*)(gp + (size_t)(g + 2) * 1024);
    __builtin_amdgcn_s_setprio(1);
    const f32x16 da = __builtin_amdgcn_mfma_f32_32x32x16_bf16(f0, bq0, zacc, 0, 0, 0);
    const f32x16 db = __builtin_amdgcn_mfma_f32_32x32x16_bf16(f0, bq1, zacc, 0, 0, 0);
    const f32x16 dc = __builtin_amdgcn_mfma_f32_32x32x16_bf16(f0, bq2, zacc, 0, 0, 0);
    const f32x16 dd = __builtin_amdgcn_mfma_f32_32x32x16_bf16(f0, bq3, zacc, 0, 0, 0);
    __builtin_amdgcn_s_setprio(0);
    mm0 = red16(da, mm0);
    mm1 = red16(db, mm1);
    mm2 = red16(dc, mm2);
    mm3 = red16(dd, mm3);
    f0 = nf0;

    const short8 nf1 = *(const short8*)(gp + (size_t)(g + 3) * 1024);
    __builtin_amdgcn_s_setprio(1);
    const f32x16 de = __builtin_amdgcn_mfma_f32_32x32x16_bf16(f1, bq0, zacc, 0, 0, 0);
    const f32x16 df = __builtin_amdgcn_mfma_f32_32x32x16_bf16(f1, bq1, zacc, 0, 0, 0);
    const f32x16 dg = __builtin_amdgcn_mfma_f32_32x32x16_bf16(f1, bq2, zacc, 0, 0, 0);
    const f32x16 dh = __builtin_amdgcn_mfma_f32_32x32x16_bf16(f1, bq3, zacc, 0, 0, 0);
    __builtin_amdgcn_s_setprio(0);
    mm0 = red16(de, mm0);
    mm1 = red16(df, mm1);
    mm2 = red16(dg, mm2);
    mm3 = red16(dh, mm3);
    f1 = nf1;
  }

  // C layout (m74/m101): col = lane&31 (query), rows split across lane^32.
  mm0 = fminf(mm0, __shfl_xor(mm0, 32));
  mm1 = fminf(mm1, __shfl_xor(mm1, 32));
  mm2 = fminf(mm2, __shfl_xor(mm2, 32));
  mm3 = fminf(mm3, __shfl_xor(mm3, 32));
  if (lane < 32) {
    if (n0 < Nq) atomicMin((unsigned int*)(o + n0), __float_as_uint(fmaxf(mm0 + sqq0, 0.f)));
    if (n1 < Nq) atomicMin((unsigned int*)(o + n1), __float_as_uint(fmaxf(mm1 + sqq1, 0.f)));
    if (n2 < Nq) atomicMin((unsigned int*)(o + n2), __float_as_uint(fmaxf(mm2 + sqq2, 0.f)));
    if (n3 < Nq) atomicMin((unsigned int*)(o + n3), __float_as_uint(fmaxf(mm3 + sqq3, 0.f)));
  }
}

extern "C" void kernel_launch(void* const* d_in, const int* in_sizes, int n_in,
                              void* d_out, int out_size, void* d_ws, size_t ws_size,
                              hipStream_t stream) {
  const float* xyz1 = (const float*)d_in[0];
  const float* xyz2 = (const float*)d_in[1];
  float* out = (float*)d_out;

  const int B = 8;                      // fixed by the reference problem
  const int N = in_sizes[0] / (B * 3);  // 8192
  const int M = in_sizes[1] / (B * 3);  // 8192

  // Outputs to huge positive float (0x7f7f7f7f) so uint atomicMin of
  // non-negative distances always wins.
  hipMemsetAsync(d_out, 0x7f, (size_t)out_size * sizeof(float), stream);

  const size_t Npad = pad512((size_t)N), Mpad = pad512((size_t)M);
  char* frags = (char*)d_ws;            // needs B*(Npad+Mpad)*32 = 4 MB here

  const size_t pmax = Npad > Mpad ? Npad : Mpad;
  dim3 g1((unsigned)(pmax / 256), 1, 2 * B);
  frag_kernel<<<g1, dim3(256), 0, stream>>>(xyz1, xyz2, frags, B, N, M);

  const int nmax = N > M ? N : M;
  const unsigned nx = (unsigned)((nmax + QPB - 1) / QPB);
  dim3 g2(nx * NSPLIT * 2 * B, 1, 1);   // id%(2B)==z -> same-z blocks share XCD
  chamfer_mfma<<<g2, dim3(256), 0, stream>>>(xyz1, xyz2, frags, out, B, N, M);
}

// Round 6
// 88.844 us; speedup vs baseline: 1.4721x; 1.0325x over previous
//
#include <hip/hip_runtime.h>
#include <math.h>

// Chamfer distance via MFMA on MI355X (gfx950).
// B=8, N=M=8192, fp32 in/out. out = concat(dist1[B*N], dist2[B*M]).
//
// d(q,c) = |q|^2 + (|c|^2 - 2 q.c). The parenthesized part is a K<=16 dot
// product on v_mfma_f32_32x32x16_bf16 with split-bf16 (hi+lo) operands; all
// four cross terms kept, plus |c|^2 embedded hi/lo against 1.0. bf16 x bf16
// products are exact in the f32 accumulator.
//
// Round 6 change (kill the AGPR round-trip): rounds 1-5 all carried a hidden
// per-MFMA tax — VGPR_Count=44 proves the f32x16 accumulators lived in
// AGPRs, so every MFMA result reached v_min3 via 16x v_accvgpr_read
// (16 moves + 8 min3 = 48 VALU cyc per 32.3-cyc MFMA -> VALU-bound, which
// is why occupancy/barrier/VMEM rewrites were all neutral). This version
// keeps at most TWO f32x16 results live (issue MFMA k+1, reduce result k,
// #pragma unroll 1) under a 128-VGPR budget (__launch_bounds__(256,4),
// still 4 waves/SIMD) so the allocator keeps accumulators in arch VGPRs.
// Diagnostic: VGPR_Count should jump to ~90-110 and the main kernel drop
// toward the 13.8 us matrix-pipe floor.
//
// Also: output init is folded into frag_kernel (one less dispatch);
// setprio dropped (MFMAs are now interleaved with min3s; holding prio
// through VALU would starve other waves' loads).
//
// NOTE (profiling): the ~41 us __amd_rocclr_fillBufferAligned dispatches are
// the harness's 256 MiB workspace poison, fixed per-iteration overhead.

typedef __attribute__((ext_vector_type(8))) short short8;
typedef __attribute__((ext_vector_type(16))) float f32x16;

#define NSPLIT 4                 // candidate quarters per (z) scan
#define QPW    128               // queries per wave (4 B-fragments)
#define QPB    (QPW * 4)         // queries per block (4 waves)

__host__ __device__ static inline size_t pad512(size_t x) {
  return (x + 511) & ~(size_t)511;
}

__device__ __forceinline__ unsigned short bf16h(float x) {
  unsigned u = __float_as_uint(x);
  return (unsigned short)((u + 0x7fffu + ((u >> 16) & 1u)) >> 16);  // RNE
}
__device__ __forceinline__ float bf16f(unsigned short h) {
  return __uint_as_float((unsigned)h << 16);
}
__device__ __forceinline__ float m3(float a, float b, float c) {
  return fminf(fminf(a, b), c);  // -> v_min3_f32
}
__device__ __forceinline__ float red16(const f32x16& d, float mm) {
  float r0 = m3(d[0], d[1], d[2]);
  float r1 = m3(d[3], d[4], d[5]);
  float r2 = m3(d[6], d[7], d[8]);
  float r3 = m3(d[9], d[10], d[11]);
  float r4 = m3(d[12], d[13], d[14]);
  return m3(m3(r0, r1, r2), m3(r3, r4, d[15]), mm);   // 8 x v_min3 total
}

// ---------------------------------------------------------------------------
// Kernel 1: transform candidate points into A-fragment layout, and
// initialize this z's output region to huge (so uint atomicMin of
// non-negative distances always wins). Per candidate j (group g=j>>5,
// row r=j&31), two 16B fragments:
//   khalf0: [Eh.x,Eh.y,Eh.z, El.x,El.y,El.z, Eh.x,Eh.y]
//   khalf1: [Eh.z, El.x,El.y,El.z, sqh, sql, 0, 0]       (E = -2c, sq = |c|^2)
// stored at frag16[g*64 + h*32 + r] == consumer byte addr g*1024 + lane*16
// with lane = h*32 + r.
// ---------------------------------------------------------------------------
__global__ __launch_bounds__(256) void frag_kernel(
    const float* __restrict__ xyz1, const float* __restrict__ xyz2,
    char* __restrict__ frags, float* __restrict__ out, int B, int N, int M)
{
  const int z = blockIdx.z, dir = z / B, b = z % B;
  const size_t Mpad = pad512((size_t)M), Npad = pad512((size_t)N);
  const float* cp; char* reg_; int Nc; size_t Pc; float* oreg; int NqO;
  if (dir == 0) {  // candidates = xyz2; this z's queries = xyz1 -> dist1[b]
    cp = xyz2 + (size_t)b * M * 3;
    reg_ = frags + (size_t)b * Mpad * 32;
    Nc = M; Pc = Mpad;
    oreg = out + (size_t)b * N; NqO = N;
  } else {         // candidates = xyz1; this z's queries = xyz2 -> dist2[b]
    cp = xyz1 + (size_t)b * N * 3;
    reg_ = frags + (size_t)B * Mpad * 32 + (size_t)b * Npad * 32;
    Nc = N; Pc = Npad;
    oreg = out + (size_t)B * N + (size_t)b * M; NqO = M;
  }
  const size_t j = (size_t)blockIdx.x * 256 + threadIdx.x;

  // output init (N==M==8192 here, so Pc covers NqO; guard anyway)
  if (j < (size_t)NqO) ((unsigned*)oreg)[j] = 0x7f7f7f7fu;
  if (j >= Pc) return;

  float x = 0.f, y = 0.f, zz = 0.f, sq = 3.0e38f;   // pad -> "infinitely far"
  if (j < (size_t)Nc) {
    x = cp[3 * j + 0]; y = cp[3 * j + 1]; zz = cp[3 * j + 2];
    sq = x * x; sq = fmaf(y, y, sq); sq = fmaf(zz, zz, sq);
  }
  const float ex = -2.f * x, ey = -2.f * y, ez = -2.f * zz;
  const unsigned short ehx = bf16h(ex); const unsigned short elx = bf16h(ex - bf16f(ehx));
  const unsigned short ehy = bf16h(ey); const unsigned short ely = bf16h(ey - bf16f(ehy));
  const unsigned short ehz = bf16h(ez); const unsigned short elz = bf16h(ez - bf16f(ehz));
  const unsigned short sh  = bf16h(sq); const unsigned short sl  = bf16h(sq - bf16f(sh));

  short8 f0, f1;
  f0[0] = (short)ehx; f0[1] = (short)ehy; f0[2] = (short)ehz; f0[3] = (short)elx;
  f0[4] = (short)ely; f0[5] = (short)elz; f0[6] = (short)ehx; f0[7] = (short)ehy;
  f1[0] = (short)ehz; f1[1] = (short)elx; f1[2] = (short)ely; f1[3] = (short)elz;
  f1[4] = (short)sh;  f1[5] = (short)sl;  f1[6] = 0;          f1[7] = 0;

  short8* fp = (short8*)reg_ + ((j >> 5) * 64 + (j & 31));
  fp[0]  = f0;    // khalf 0
  fp[32] = f1;    // khalf 1
}

// Query B-fragment (pairs slot-for-slot with the candidate fragment):
//   khalf0: [Qh.x,Qh.y,Qh.z, Qh.x,Qh.y,Qh.z, Ql.x,Ql.y]
//   khalf1: [Ql.z, Ql.x,Ql.y,Ql.z, 1.0, 1.0, 0, 0]
// Slot products sum to  q.(-2c) + |c|^2  exactly as packed.
__device__ __forceinline__ short8 make_qfrag(float x, float y, float z, int hi) {
  const unsigned short hx = bf16h(x); const unsigned short lx = bf16h(x - bf16f(hx));
  const unsigned short hy = bf16h(y); const unsigned short ly = bf16h(y - bf16f(hy));
  const unsigned short hz = bf16h(z); const unsigned short lz = bf16h(z - bf16f(hz));
  const unsigned short ONE = 0x3F80;
  short8 f;
  if (hi == 0) {
    f[0] = (short)hx; f[1] = (short)hy; f[2] = (short)hz; f[3] = (short)hx;
    f[4] = (short)hy; f[5] = (short)hz; f[6] = (short)lx; f[7] = (short)ly;
  } else {
    f[0] = (short)lz; f[1] = (short)lx; f[2] = (short)ly; f[3] = (short)lz;
    f[4] = (short)ONE; f[5] = (short)ONE; f[6] = 0; f[7] = 0;
  }
  return f;
}

// ---------------------------------------------------------------------------
// Kernel 2: 256 threads (4 waves), no LDS, no barriers. Each wave owns 128
// queries (4 B-frags) and streams its candidate quarter global->register
// with depth-2 prefetch. Per A-fragment: 4 MFMA + 4 red16, rotated one step
// so at most TWO f32x16 results are live (keeps accumulators in VGPRs).
// Partial minima merge via uint atomicMin.
// Grid is 1D with id%(2B) == z so same-z blocks share an XCD's L2.
// ---------------------------------------------------------------------------
__global__ __launch_bounds__(256, 4) void chamfer_mfma(
    const float* __restrict__ xyz1, const float* __restrict__ xyz2,
    const char* __restrict__ frags, float* __restrict__ out,
    int B, int N, int M)
{
  const int id   = (int)blockIdx.x;
  const int z    = id % (2 * B);          // fastest -> XCD (%8) keyed by z
  const int rest = id / (2 * B);
  const int by   = rest % NSPLIT;
  const int bx   = rest / NSPLIT;

  const int dir = z / B, b = z % B;
  const size_t Mpad = pad512((size_t)M), Npad = pad512((size_t)N);
  const float* qp; float* o; const char* fr; int Nq, Nc;
  if (dir == 0) {   // queries = xyz1, candidates = xyz2
    qp = xyz1 + (size_t)b * N * 3;
    o  = out + (size_t)b * N;
    fr = frags + (size_t)b * Mpad * 32;
    Nq = N; Nc = (int)Mpad;
  } else {          // queries = xyz2, candidates = xyz1
    qp = xyz2 + (size_t)b * M * 3;
    o  = out + (size_t)B * N + (size_t)b * M;
    fr = frags + (size_t)B * Mpad * 32 + (size_t)b * Npad * 32;
    Nq = M; Nc = (int)Npad;
  }
  if (bx * QPB >= Nq) return;   // block-uniform early out

  const int lane = threadIdx.x & 63;
  const int wid  = threadIdx.x >> 6;
  const int hi   = lane >> 5;

  // ---- candidate quarter: gq groups of 32 (gq even) ----
  const int gq = Nc / (32 * NSPLIT);
  const char* gp = fr + (size_t)by * gq * 1024 + (size_t)lane * 16;

  // ---- four query sets per wave ----
  const int qbase = bx * QPB + wid * QPW;
  const int n0 = qbase + (lane & 31);
  const int n1 = n0 + 32;
  const int n2 = n0 + 64;
  const int n3 = n0 + 96;
  const int n0c = n0 < Nq ? n0 : Nq - 1;
  const int n1c = n1 < Nq ? n1 : Nq - 1;
  const int n2c = n2 < Nq ? n2 : Nq - 1;
  const int n3c = n3 < Nq ? n3 : Nq - 1;
  const float q0x = qp[3 * n0c], q0y = qp[3 * n0c + 1], q0z = qp[3 * n0c + 2];
  const float q1x = qp[3 * n1c], q1y = qp[3 * n1c + 1], q1z = qp[3 * n1c + 2];
  const float q2x = qp[3 * n2c], q2y = qp[3 * n2c + 1], q2z = qp[3 * n2c + 2];
  const float q3x = qp[3 * n3c], q3y = qp[3 * n3c + 1], q3z = qp[3 * n3c + 2];
  float sqq0 = q0x * q0x; sqq0 = fmaf(q0y, q0y, sqq0); sqq0 = fmaf(q0z, q0z, sqq0);
  float sqq1 = q1x * q1x; sqq1 = fmaf(q1y, q1y, sqq1); sqq1 = fmaf(q1z, q1z, sqq1);
  float sqq2 = q2x * q2x; sqq2 = fmaf(q2y, q2y, sqq2); sqq2 = fmaf(q2z, q2z, sqq2);
  float sqq3 = q3x * q3x; sqq3 = fmaf(q3y, q3y, sqq3); sqq3 = fmaf(q3z, q3z, sqq3);
  const short8 bq0 = make_qfrag(q0x, q0y, q0z, hi);
  const short8 bq1 = make_qfrag(q1x, q1y, q1z, hi);
  const short8 bq2 = make_qfrag(q2x, q2y, q2z, hi);
  const short8 bq3 = make_qfrag(q3x, q3y, q3z, hi);

  const f32x16 zacc = {0.f,0.f,0.f,0.f,0.f,0.f,0.f,0.f,
                       0.f,0.f,0.f,0.f,0.f,0.f,0.f,0.f};
  float mm0 = 3.0e38f, mm1 = 3.0e38f, mm2 = 3.0e38f, mm3 = 3.0e38f;

  // depth-2 register prefetch. Prefetch may run up to 2 KB past the quarter
  // (and, for the last quarter of the last z, past the 4 MB frag region) —
  // values are never consumed and the workspace is >=256 MB, so it's safe.
  short8 f0 = *(const short8*)(gp);
  short8 f1 = *(const short8*)(gp + 1024);
#pragma unroll 1
  for (int g = 0; g < gq; g += 2) {
    const short8 nf0 = *(const short8*)(gp + (size_t)(g + 2) * 1024);
    {
      // rotated: issue MFMA k+1, then reduce result k  (max 2 live f32x16)
      f32x16 d0 = __builtin_amdgcn_mfma_f32_32x32x16_bf16(f0, bq0, zacc, 0, 0, 0);
      f32x16 d1 = __builtin_amdgcn_mfma_f32_32x32x16_bf16(f0, bq1, zacc, 0, 0, 0);
      mm0 = red16(d0, mm0);
      f32x16 d2 = __builtin_amdgcn_mfma_f32_32x32x16_bf16(f0, bq2, zacc, 0, 0, 0);
      mm1 = red16(d1, mm1);
      f32x16 d3 = __builtin_amdgcn_mfma_f32_32x32x16_bf16(f0, bq3, zacc, 0, 0, 0);
      mm2 = red16(d2, mm2);
      mm3 = red16(d3, mm3);
    }
    f0 = nf0;

    const short8 nf1 = *(const short8*)(gp + (size_t)(g + 3) * 1024);
    {
      f32x16 d0 = __builtin_amdgcn_mfma_f32_32x32x16_bf16(f1, bq0, zacc, 0, 0, 0);
      f32x16 d1 = __builtin_amdgcn_mfma_f32_32x32x16_bf16(f1, bq1, zacc, 0, 0, 0);
      mm0 = red16(d0, mm0);
      f32x16 d2 = __builtin_amdgcn_mfma_f32_32x32x16_bf16(f1, bq2, zacc, 0, 0, 0);
      mm1 = red16(d1, mm1);
      f32x16 d3 = __builtin_amdgcn_mfma_f32_32x32x16_bf16(f1, bq3, zacc, 0, 0, 0);
      mm2 = red16(d2, mm2);
      mm3 = red16(d3, mm3);
    }
    f1 = nf1;
  }

  // C layout (m74/m101): col = lane&31 (query), rows split across lane^32.
  mm0 = fminf(mm0, __shfl_xor(mm0, 32));
  mm1 = fminf(mm1, __shfl_xor(mm1, 32));
  mm2 = fminf(mm2, __shfl_xor(mm2, 32));
  mm3 = fminf(mm3, __shfl_xor(mm3, 32));
  if (lane < 32) {
    if (n0 < Nq) atomicMin((unsigned int*)(o + n0), __float_as_uint(fmaxf(mm0 + sqq0, 0.f)));
    if (n1 < Nq) atomicMin((unsigned int*)(o + n1), __float_as_uint(fmaxf(mm1 + sqq1, 0.f)));
    if (n2 < Nq) atomicMin((unsigned int*)(o + n2), __float_as_uint(fmaxf(mm2 + sqq2, 0.f)));
    if (n3 < Nq) atomicMin((unsigned int*)(o + n3), __float_as_uint(fmaxf(mm3 + sqq3, 0.f)));
  }
}

extern "C" void kernel_launch(void* const* d_in, const int* in_sizes, int n_in,
                              void* d_out, int out_size, void* d_ws, size_t ws_size,
                              hipStream_t stream) {
  const float* xyz1 = (const float*)d_in[0];
  const float* xyz2 = (const float*)d_in[1];
  float* out = (float*)d_out;

  const int B = 8;                      // fixed by the reference problem
  const int N = in_sizes[0] / (B * 3);  // 8192
  const int M = in_sizes[1] / (B * 3);  // 8192

  const size_t Npad = pad512((size_t)N), Mpad = pad512((size_t)M);
  char* frags = (char*)d_ws;            // needs B*(Npad+Mpad)*32 = 4 MB here

  const size_t pmax = Npad > Mpad ? Npad : Mpad;
  dim3 g1((unsigned)(pmax / 256), 1, 2 * B);
  frag_kernel<<<g1, dim3(256), 0, stream>>>(xyz1, xyz2, frags, out, B, N, M);

  const int nmax = N > M ? N : M;
  const unsigned nx = (unsigned)((nmax + QPB - 1) / QPB);
  dim3 g2(nx * NSPLIT * 2 * B, 1, 1);   // id%(2B)==z -> same-z blocks share XCD
  chamfer_mfma<<<g2, dim3(256), 0, stream>>>(xyz1, xyz2, frags, out, B, N, M);
}